// Round 4
// baseline (1142.188 us; speedup 1.0000x reference)
//
#include <hip/hip_runtime.h>
#include <hip/hip_bf16.h>
#include <hip/hip_cooperative_groups.h>
#include <stdint.h>

namespace cg = cooperative_groups;
typedef __hip_bfloat16 bf16;

#define VOCABN 100000
#define EDIM 128
#define BN 16
#define SN 2048
#define NCH 16
#define NB 1024
#define NTH 256
#define NWAVES (NB * 4)

// ws float offsets
#define H_OFF    0
#define U_OFF    2048
#define L_OFF    4096
#define P_OFF    36864
#define RS_OFF   69632
#define PBV_OFF  69648
#define PBI_OFF  70848
#define AMAX_OFF 72048
#define PART_OFF 2000000   // fallback-path partials (32768 floats), clear of everything
#define G_OFF    73728     // u32 region, 3*16*2048*64 = 6291456 u32

// ---------- threefry2x32 (JAX partitionable) ----------
__host__ __device__ inline void tf2x32(uint32_t k0, uint32_t k1,
                                       uint32_t x0, uint32_t x1,
                                       uint32_t* o0, uint32_t* o1) {
  const uint32_t rotA[4] = {13u, 15u, 26u, 6u};
  const uint32_t rotB[4] = {17u, 29u, 16u, 24u};
  uint32_t ks0 = k0, ks1 = k1, ks2 = k0 ^ k1 ^ 0x1BD11BDAu;
  x0 += ks0; x1 += ks1;
#pragma unroll
  for (int g = 0; g < 5; ++g) {
    const uint32_t* r = (g & 1) ? rotB : rotA;
#pragma unroll
    for (int i = 0; i < 4; ++i) {
      x0 += x1;
      x1 = (x1 << r[i]) | (x1 >> (32u - r[i]));
      x1 ^= x0;
    }
    uint32_t a0 = (g % 3 == 0) ? ks1 : ((g % 3 == 1) ? ks2 : ks0);
    uint32_t a1 = (g % 3 == 0) ? ks2 : ((g % 3 == 1) ? ks0 : ks1);
    x0 += a0;
    x1 += a1 + (uint32_t)(g + 1);
  }
  *o0 = x0; *o1 = x1;
}

__device__ inline float blo(uint32_t v) { return __uint_as_float(v << 16); }
__device__ inline float bhi(uint32_t v) { return __uint_as_float(v & 0xffff0000u); }
__device__ inline uint16_t f2bu(float f) {
  bf16 h = __float2bfloat16(f);
  uint16_t u; __builtin_memcpy(&u, &h, 2); return u;
}
__device__ inline float gumbel(uint32_t ka, uint32_t kb, uint32_t flat) {
  uint32_t o0, o1;
  tf2x32(ka, kb, 0u, flat, &o0, &o1);
  uint32_t bits = o0 ^ o1;
  float u0 = __uint_as_float((bits >> 9) | 0x3f800000u) - 1.0f;
  float uu = fmaxf(1e-10f, u0 + 1e-10f);
  return -logf(-logf(uu));
}

struct Params {
  const int* story; const int* lengths; const float* hidden; const float* C;
  const float* Wm; const float* Wb; const float* W1w; const float* W1b;
  const float* W3w; const float* W3b; const float* W4w; const float* W4b;
  float* out; float* ws;
  uint32_t k0a, k0b, k1a, k1b, k2a, k2b;
};

// ================= MEGA (cooperative) =================
__global__ void __launch_bounds__(NTH, 4) mega(Params p) {
  cg::grid_group grid = cg::this_grid();
  const int bid = blockIdx.x, tid = threadIdx.x;
  const int wave = tid >> 6, lane = tid & 63;
  const int gw = bid * 4 + wave;

  float* h  = p.ws + H_OFF;
  float* u  = p.ws + U_OFF;
  float* l  = p.ws + L_OFF;
  float* pr = p.ws + P_OFF;
  float* rs = p.ws + RS_OFF;
  float* pbv = p.ws + PBV_OFF;
  int*   pbi = (int*)(p.ws + PBI_OFF);
  int*   amax = (int*)(p.ws + AMAX_OFF);
  uint32_t* G = (uint32_t*)(p.ws + G_OFF);

  __shared__ __align__(16) union {
    float row[2048];
    struct { float hb[128]; float sv[256]; } hd;
    struct { float ps[128]; float acc[4][128]; } up;
  } sm;
  __shared__ int si[256];
  __shared__ float redX[8];

  // ---------- P0: h,u + gather G0..G2 ----------
  {
    int gtid = bid * NTH + tid;
    if (gtid < 2048) {
      int b = gtid >> 7, j = gtid & 127;
      const float4* wr = (const float4*)(p.Wm + (size_t)j * EDIM);
      const float4* hr = (const float4*)(p.hidden + (size_t)b * EDIM);
      float acc = p.Wb[j];
#pragma unroll
      for (int i = 0; i < 32; ++i) {
        float4 w4 = wr[i], h4 = hr[i];
        acc += w4.x * h4.x + w4.y * h4.y + w4.z * h4.z + w4.w * h4.w;
      }
      h[gtid] = acc; u[gtid] = acc;
    }
    for (int cell = gw; cell < 3 * BN * SN; cell += NWAVES) {
      int t = cell >> 15;
      int bs = cell & 32767;
      int4 idx = ((const int4*)p.story)[bs];
      const float2* r0 = (const float2*)(p.C + ((size_t)t * VOCABN + idx.x) * EDIM);
      const float2* r1 = (const float2*)(p.C + ((size_t)t * VOCABN + idx.y) * EDIM);
      const float2* r2 = (const float2*)(p.C + ((size_t)t * VOCABN + idx.z) * EDIM);
      const float2* r3 = (const float2*)(p.C + ((size_t)t * VOCABN + idx.w) * EDIM);
      float2 a = r0[lane], b = r1[lane], c = r2[lane], d = r3[lane];
      float lo = a.x + b.x + c.x + d.x;
      float hi = a.y + b.y + c.y + d.y;
      G[(size_t)cell * 64 + lane] = (uint32_t)f2bu(lo) | ((uint32_t)f2bu(hi) << 16);
    }
  }
  grid.sync();

  // ---------- P1: heads (blocks 0..431) || logits hop0 (blocks 432..1023) ----------
  if (bid < 432) {
    int head, b2, base, cnt, chunk, N;
    const float *W, *bias; size_t lg_off; uint32_t ka, kb;
    if (bid < 400)      { head = 1; b2 = bid / 25; chunk = bid % 25; base = chunk * 160; cnt = 160;
                          W = p.W3w; bias = p.W3b; N = 4000; lg_off = 64;     ka = p.k1a; kb = p.k1b; }
    else if (bid < 416) { head = 2; b2 = bid - 400; chunk = 0; base = 0; cnt = 200;
                          W = p.W4w; bias = p.W4b; N = 200;  lg_off = 128064; ka = p.k2a; kb = p.k2b; }
    else                { head = 0; b2 = bid - 416; chunk = 0; base = 0; cnt = 2;
                          W = p.W1w; bias = p.W1b; N = 2;    lg_off = 0;      ka = p.k0a; kb = p.k0b; }
    if (tid < 128) sm.hd.hb[tid] = h[b2 * EDIM + tid];
    __syncthreads();
    float best = -INFINITY; int bi = 0x7FFFFFFF;
    if (tid < cnt) {
      int c = base + tid;
      const float4* wr = (const float4*)(W + (size_t)c * EDIM);
      const float4* hb4 = (const float4*)sm.hd.hb;
      float acc = bias[c];
#pragma unroll
      for (int i = 0; i < 32; ++i) {
        float4 w4 = wr[i], h4 = hb4[i];
        acc += w4.x * h4.x + w4.y * h4.y + w4.z * h4.z + w4.w * h4.w;
      }
      p.out[lg_off + (size_t)b2 * N + c] = acc;
      float z = acc + gumbel(ka, kb, (uint32_t)(b2 * N + c));
      best = z; bi = c;
    }
    sm.hd.sv[tid] = best; si[tid] = bi;
    __syncthreads();
    for (int s2 = 128; s2 > 0; s2 >>= 1) {
      if (tid < s2) {
        float ov = sm.hd.sv[tid + s2]; int oi = si[tid + s2];
        if (ov > sm.hd.sv[tid] || (ov == sm.hd.sv[tid] && oi < si[tid])) {
          sm.hd.sv[tid] = ov; si[tid] = oi;
        }
      }
      __syncthreads();
    }
    if (tid == 0) {
      pbv[(head * 16 + b2) * 25 + chunk] = sm.hd.sv[0];
      pbi[(head * 16 + b2) * 25 + chunk] = si[0];
    }
  } else {
    int lw = (bid - 432) * 4 + wave;
    for (int cell = lw; cell < BN * SN; cell += 592 * 4) {
      uint32_t v = G[(size_t)cell * 64 + lane];   // G0
      float2 uu = ((const float2*)(u + ((cell >> 11) << 7)))[lane];
      float s = blo(v) * uu.x + bhi(v) * uu.y;
#pragma unroll
      for (int off = 32; off > 0; off >>= 1) s += __shfl_xor(s, off, 64);
      if (lane == 0) l[cell] = s;
    }
  }
  grid.sync();

  // ---------- P2: softmax hop0 (blocks 0..15) + argmax finalize (block 16) ----------
  if (bid < 16) {
    const float* lr = l + bid * SN;
    float m = -INFINITY;
    for (int s = tid; s < SN; s += NTH) { float v = lr[s]; sm.row[s] = v; m = fmaxf(m, v); }
#pragma unroll
    for (int off = 32; off > 0; off >>= 1) m = fmaxf(m, __shfl_xor(m, off, 64));
    if (lane == 0) redX[wave] = m;
    __syncthreads();
    m = fmaxf(fmaxf(redX[0], redX[1]), fmaxf(redX[2], redX[3]));
    float sum = 0.f;
    for (int s = tid; s < SN; s += NTH) { float e = expf(sm.row[s] - m); pr[bid * SN + s] = e; sum += e; }
#pragma unroll
    for (int off = 32; off > 0; off >>= 1) sum += __shfl_xor(sum, off, 64);
    if (lane == 0) redX[4 + wave] = sum;
    __syncthreads();
    if (tid == 0) rs[bid] = redX[4] + redX[5] + redX[6] + redX[7];
  } else if (bid == 16 && tid < 48) {
    int head = tid / 16, b2 = tid % 16;
    int nch = (head == 1) ? 25 : 1;
    float bv = -INFINITY; int bi = 0x7FFFFFFF;
    for (int ch = 0; ch < nch; ++ch) {
      float v = pbv[(head * 16 + b2) * 25 + ch];
      int i2 = pbi[(head * 16 + b2) * 25 + ch];
      if (v > bv || (v == bv && i2 < bi)) { bv = v; bi = i2; }
    }
    amax[head * 16 + b2] = bi;
  }
  grid.sync();

  // ---------- P3: u-update hop0 (blocks 0..255, G1) || one-hots (blocks 256..) ----------
  if (bid < 256) {
    const uint32_t* G1 = G + (size_t)1 * BN * SN * 64;
    int b2 = bid >> 4, ch = bid & 15;
    if (tid < 128) sm.up.ps[tid] = pr[b2 * SN + ch * 128 + tid];
    __syncthreads();
    float inv = 1.0f / rs[b2];
    float ax = 0.f, ay = 0.f;
    for (int s = wave; s < 128; s += 4) {
      uint32_t v = G1[((size_t)(b2 * SN + ch * 128 + s)) * 64 + lane];
      float pp = sm.up.ps[s];
      ax += blo(v) * pp; ay += bhi(v) * pp;
    }
    sm.up.acc[wave][2 * lane] = ax; sm.up.acc[wave][2 * lane + 1] = ay;
    __syncthreads();
    if (tid < 128) {
      float r = (sm.up.acc[0][tid] + sm.up.acc[1][tid] + sm.up.acc[2][tid] + sm.up.acc[3][tid]) * inv;
      atomicAdd(u + b2 * EDIM + tid, r);
    }
  } else {
    int g = (bid - 256) * NTH + tid;
    if (g < 67232) {
      if (g < 64000) {
        int b2 = g / 4000, c = g % 4000;
        p.out[64064 + g] = (c == amax[16 + b2]) ? 1.0f : 0.0f;
      } else if (g < 67200) {
        int gg = g - 64000; int b2 = gg / 200, c = gg % 200;
        p.out[131264 + gg] = (c == amax[32 + b2]) ? 1.0f : 0.0f;
      } else {
        int gg = g - 67200; int b2 = gg >> 1, c = gg & 1;
        p.out[32 + gg] = (c == amax[b2]) ? 1.0f : 0.0f;
      }
    }
  }
  grid.sync();

  // ---------- P4: logits hop1 (G1, u) ----------
  {
    const uint32_t* G1 = G + (size_t)1 * BN * SN * 64;
    for (int cell = gw; cell < BN * SN; cell += NWAVES) {
      uint32_t v = G1[(size_t)cell * 64 + lane];
      float2 uu = ((const float2*)(u + ((cell >> 11) << 7)))[lane];
      float s = blo(v) * uu.x + bhi(v) * uu.y;
#pragma unroll
      for (int off = 32; off > 0; off >>= 1) s += __shfl_xor(s, off, 64);
      if (lane == 0) l[cell] = s;
    }
  }
  grid.sync();

  // ---------- P5: softmax hop1 ----------
  if (bid < 16) {
    const float* lr = l + bid * SN;
    float m = -INFINITY;
    for (int s = tid; s < SN; s += NTH) { float v = lr[s]; sm.row[s] = v; m = fmaxf(m, v); }
#pragma unroll
    for (int off = 32; off > 0; off >>= 1) m = fmaxf(m, __shfl_xor(m, off, 64));
    if (lane == 0) redX[wave] = m;
    __syncthreads();
    m = fmaxf(fmaxf(redX[0], redX[1]), fmaxf(redX[2], redX[3]));
    float sum = 0.f;
    for (int s = tid; s < SN; s += NTH) { float e = expf(sm.row[s] - m); pr[bid * SN + s] = e; sum += e; }
#pragma unroll
    for (int off = 32; off > 0; off >>= 1) sum += __shfl_xor(sum, off, 64);
    if (lane == 0) redX[4 + wave] = sum;
    __syncthreads();
    if (tid == 0) rs[bid] = redX[4] + redX[5] + redX[6] + redX[7];
  }
  grid.sync();

  // ---------- P6: u-update hop1 (G2) ----------
  if (bid < 256) {
    const uint32_t* G2 = G + (size_t)2 * BN * SN * 64;
    int b2 = bid >> 4, ch = bid & 15;
    if (tid < 128) sm.up.ps[tid] = pr[b2 * SN + ch * 128 + tid];
    __syncthreads();
    float inv = 1.0f / rs[b2];
    float ax = 0.f, ay = 0.f;
    for (int s = wave; s < 128; s += 4) {
      uint32_t v = G2[((size_t)(b2 * SN + ch * 128 + s)) * 64 + lane];
      float pp = sm.up.ps[s];
      ax += blo(v) * pp; ay += bhi(v) * pp;
    }
    sm.up.acc[wave][2 * lane] = ax; sm.up.acc[wave][2 * lane + 1] = ay;
    __syncthreads();
    if (tid < 128) {
      float r = (sm.up.acc[0][tid] + sm.up.acc[1][tid] + sm.up.acc[2][tid] + sm.up.acc[3][tid]) * inv;
      atomicAdd(u + b2 * EDIM + tid, r);
    }
  }
  grid.sync();

  // ---------- P7: logits hop2 + masked sigmoid store ----------
  {
    const uint32_t* G2 = G + (size_t)2 * BN * SN * 64;
    for (int cell = gw; cell < BN * SN; cell += NWAVES) {
      uint32_t v = G2[(size_t)cell * 64 + lane];
      float2 uu = ((const float2*)(u + ((cell >> 11) << 7)))[lane];
      float s = blo(v) * uu.x + bhi(v) * uu.y;
#pragma unroll
      for (int off = 32; off > 0; off >>= 1) s += __shfl_xor(s, off, 64);
      if (lane == 0) {
        int b2 = cell >> 11, s2 = cell & 2047;
        p.out[134464 + cell] = (s2 < p.lengths[b2]) ? 1.0f / (1.0f + expf(-s)) : 0.0f;
      }
    }
  }
}

// ================= FALLBACK (round-3 proven path) =================
__global__ void k_h(const float* __restrict__ hidden, const float* __restrict__ Wm,
                    const float* __restrict__ Wb, float* __restrict__ h,
                    float* __restrict__ u) {
  int b = blockIdx.x, j = threadIdx.x;
  __shared__ float hs[EDIM];
  hs[j] = hidden[b * EDIM + j];
  __syncthreads();
  const float4* w = (const float4*)(Wm + (size_t)j * EDIM);
  float acc = Wb[j];
#pragma unroll
  for (int i = 0; i < 32; ++i) {
    float4 v = w[i];
    acc += hs[4 * i] * v.x + hs[4 * i + 1] * v.y + hs[4 * i + 2] * v.z + hs[4 * i + 3] * v.w;
  }
  h[b * EDIM + j] = acc;
  u[b * EDIM + j] = acc;
}

__global__ void k_head(const float* __restrict__ h, const float* __restrict__ W,
                       const float* __restrict__ bias, float* __restrict__ out_logit,
                       float* __restrict__ out_action, int N, uint32_t k0, uint32_t k1) {
  int b = blockIdx.x, tid = threadIdx.x;
  __shared__ float hs[EDIM];
  __shared__ float sv[256];
  __shared__ int si2[256];
  if (tid < EDIM) hs[tid] = h[b * EDIM + tid];
  __syncthreads();
  float best = -INFINITY; int bidx = 0x7FFFFFFF;
  for (int c = tid; c < N; c += 256) {
    const float4* w4 = (const float4*)(W + (size_t)c * EDIM);
    float acc = bias[c];
#pragma unroll
    for (int i = 0; i < 32; ++i) {
      float4 v = w4[i];
      acc += hs[4 * i] * v.x + hs[4 * i + 1] * v.y + hs[4 * i + 2] * v.z + hs[4 * i + 3] * v.w;
    }
    out_logit[(size_t)b * N + c] = acc;
    float z = acc + gumbel(k0, k1, (uint32_t)(b * N + c));
    if (z > best) { best = z; bidx = c; }
  }
  sv[tid] = best; si2[tid] = bidx;
  __syncthreads();
  for (int s = 128; s > 0; s >>= 1) {
    if (tid < s) {
      if (sv[tid + s] > sv[tid] || (sv[tid + s] == sv[tid] && si2[tid + s] < si2[tid])) {
        sv[tid] = sv[tid + s]; si2[tid] = si2[tid + s];
      }
    }
    __syncthreads();
  }
  int arg = si2[0];
  for (int c = tid; c < N; c += 256)
    out_action[(size_t)b * N + c] = (c == arg ? 1.0f : 0.0f);
}

__global__ void k_gather(const int* __restrict__ story, const float* __restrict__ C,
                         uint32_t* __restrict__ G) {
  int wid = (blockIdx.x << 2) | (threadIdx.x >> 6);
  int lane = threadIdx.x & 63;
  int t = wid / (BN * SN);
  int bs = wid % (BN * SN);
  int4 idx = ((const int4*)story)[bs];
  const float2* r0 = (const float2*)(C + ((size_t)t * VOCABN + idx.x) * EDIM);
  const float2* r1 = (const float2*)(C + ((size_t)t * VOCABN + idx.y) * EDIM);
  const float2* r2 = (const float2*)(C + ((size_t)t * VOCABN + idx.z) * EDIM);
  const float2* r3 = (const float2*)(C + ((size_t)t * VOCABN + idx.w) * EDIM);
  float2 a = r0[lane], b = r1[lane], c = r2[lane], d = r3[lane];
  G[(size_t)wid * 64 + lane] = (uint32_t)f2bu(a.x + b.x + c.x + d.x) |
                               ((uint32_t)f2bu(a.y + b.y + c.y + d.y) << 16);
}

__global__ void k_logits(const uint32_t* __restrict__ Gt, const float* __restrict__ u,
                         float* __restrict__ l) {
  int wid = (blockIdx.x << 2) | (threadIdx.x >> 6);
  int lane = threadIdx.x & 63;
  int b = wid >> 11;
  uint32_t v = Gt[(size_t)wid * 64 + lane];
  float2 uu = ((const float2*)(u + b * EDIM))[lane];
  float part = blo(v) * uu.x + bhi(v) * uu.y;
#pragma unroll
  for (int off = 32; off > 0; off >>= 1) part += __shfl_xor(part, off, 64);
  if (lane == 0) l[wid] = part;
}

__global__ void k_softmax(const float* __restrict__ l, float* __restrict__ p) {
  int b = blockIdx.x, tid = threadIdx.x;
  __shared__ float red[256];
  const float* lb = l + b * SN;
  float* pb = p + b * SN;
  float m = -INFINITY;
  for (int s = tid; s < SN; s += 256) m = fmaxf(m, lb[s]);
  red[tid] = m; __syncthreads();
  for (int s = 128; s > 0; s >>= 1) { if (tid < s) red[tid] = fmaxf(red[tid], red[tid + s]); __syncthreads(); }
  m = red[0]; __syncthreads();
  float sum = 0.0f;
  for (int s = tid; s < SN; s += 256) { float e = expf(lb[s] - m); pb[s] = e; sum += e; }
  red[tid] = sum; __syncthreads();
  for (int s = 128; s > 0; s >>= 1) { if (tid < s) red[tid] += red[tid + s]; __syncthreads(); }
  float inv = 1.0f / red[0];
  for (int s = tid; s < SN; s += 256) pb[s] *= inv;
}

__global__ void k_upartial(const uint32_t* __restrict__ Gt, const float* __restrict__ p,
                           float* __restrict__ part) {
  int b = blockIdx.x >> 4;
  int ch = blockIdx.x & 15;
  int w = threadIdx.x >> 6, lane = threadIdx.x & 63;
  __shared__ float ps[128];
  __shared__ float acc_s[4][EDIM];
  if (threadIdx.x < 128) ps[threadIdx.x] = p[b * SN + ch * 128 + threadIdx.x];
  __syncthreads();
  float ax = 0.0f, ay = 0.0f;
  for (int s = w; s < 128; s += 4) {
    uint32_t v = Gt[((size_t)(b * SN + ch * 128 + s)) * 64 + lane];
    float pp = ps[s];
    ax += blo(v) * pp; ay += bhi(v) * pp;
  }
  acc_s[w][2 * lane] = ax; acc_s[w][2 * lane + 1] = ay;
  __syncthreads();
  if (threadIdx.x < EDIM) {
    part[(size_t)(b * NCH + ch) * EDIM + threadIdx.x] =
        acc_s[0][threadIdx.x] + acc_s[1][threadIdx.x] + acc_s[2][threadIdx.x] + acc_s[3][threadIdx.x];
  }
}

__global__ void k_ureduce(const float* __restrict__ part, float* __restrict__ u) {
  int b = blockIdx.x, e = threadIdx.x;
  float r = 0.0f;
#pragma unroll
  for (int ch = 0; ch < NCH; ++ch) r += part[(size_t)(b * NCH + ch) * EDIM + e];
  u[b * EDIM + e] += r;
}

__global__ void k_final(const float* __restrict__ l, const int* __restrict__ lengths,
                        float* __restrict__ out) {
  int i = blockIdx.x * 256 + threadIdx.x;
  int b = i >> 11, s = i & 2047;
  float v = l[i];
  out[i] = (s < lengths[b]) ? 1.0f / (1.0f + expf(-v)) : 0.0f;
}

extern "C" void kernel_launch(void* const* d_in, const int* in_sizes, int n_in,
                              void* d_out, int out_size, void* d_ws, size_t ws_size,
                              hipStream_t stream) {
  const int *story = nullptr, *lengths = nullptr;
  const float *hidden = nullptr, *C = nullptr, *Wm = nullptr, *Wb = nullptr,
              *W1w = nullptr, *W1b = nullptr, *W3w = nullptr, *W3b = nullptr,
              *W4w = nullptr, *W4b = nullptr;
  for (int i = 0; i < n_in; ++i) {
    switch (in_sizes[i]) {
      case 16 * 2048 * 4:    story   = (const int*)d_in[i]; break;
      case 16:               lengths = (const int*)d_in[i]; break;
      case 16 * 128:         hidden  = (const float*)d_in[i]; break;
      case 4 * 100000 * 128: C       = (const float*)d_in[i]; break;
      case 128 * 128:        Wm      = (const float*)d_in[i]; break;
      case 128:              Wb      = (const float*)d_in[i]; break;
      case 2 * 128:          W1w     = (const float*)d_in[i]; break;
      case 2:                W1b     = (const float*)d_in[i]; break;
      case 4000 * 128:       W3w     = (const float*)d_in[i]; break;
      case 4000:             W3b     = (const float*)d_in[i]; break;
      case 200 * 128:        W4w     = (const float*)d_in[i]; break;
      case 200:              W4b     = (const float*)d_in[i]; break;
      default: break;
    }
  }
  float* out = (float*)d_out;
  float* ws = (float*)d_ws;

  uint32_t k0a, k0b, k1a, k1b, k2a, k2b;
  tf2x32(0u, 42u, 0u, 0u, &k0a, &k0b);
  tf2x32(0u, 42u, 0u, 1u, &k1a, &k1b);
  tf2x32(0u, 42u, 0u, 2u, &k2a, &k2b);

  Params prm = { story, lengths, hidden, C, Wm, Wb, W1w, W1b, W3w, W3b, W4w, W4b,
                 out, ws, k0a, k0b, k1a, k1b, k2a, k2b };
  void* kargs[] = { (void*)&prm };
  hipError_t err = hipLaunchCooperativeKernel((const void*)mega, dim3(NB), dim3(NTH),
                                              kargs, 0, stream);
  if (err != hipSuccess) {
    // Fallback: proven multi-kernel path
    float* h = ws + H_OFF;  float* u = ws + U_OFF;
    float* l = ws + L_OFF;  float* p = ws + P_OFF;
    float* part = ws + PART_OFF;
    uint32_t* G = (uint32_t*)(ws + G_OFF);
    k_h<<<BN, 128, 0, stream>>>(hidden, Wm, Wb, h, u);
    k_head<<<BN, 256, 0, stream>>>(h, W1w, W1b, out + 0,      out + 32,     2,    k0a, k0b);
    k_head<<<BN, 256, 0, stream>>>(h, W3w, W3b, out + 64,     out + 64064,  4000, k1a, k1b);
    k_head<<<BN, 256, 0, stream>>>(h, W4w, W4b, out + 128064, out + 131264, 200,  k2a, k2b);
    k_gather<<<3 * BN * SN / 4, 256, 0, stream>>>(story, C, G);
    for (int hop = 0; hop < 3; ++hop) {
      const uint32_t* Gt = G + (size_t)hop * BN * SN * 64;
      k_logits<<<BN * SN / 4, 256, 0, stream>>>(Gt, u, l);
      if (hop < 2) {
        k_softmax<<<BN, 256, 0, stream>>>(l, p);
        const uint32_t* Gn = G + (size_t)(hop + 1) * BN * SN * 64;
        k_upartial<<<BN * NCH, 256, 0, stream>>>(Gn, p, part);
        k_ureduce<<<BN, EDIM, 0, stream>>>(part, u);
      }
    }
    k_final<<<BN * SN / 256, 256, 0, stream>>>(l, lengths, out + 134464);
  }
}

// Round 5
// 356.007 us; speedup vs baseline: 3.2083x; 3.2083x over previous
//
#include <hip/hip_runtime.h>
#include <hip/hip_bf16.h>
#include <stdint.h>

typedef __hip_bfloat16 bf16;

#define VOCABN 100000
#define EDIM 128
#define BN 16
#define SN 2048

// ws float offsets
#define H_OFF    0
#define U_OFF    2048
#define L0_OFF   4096      // 32768 floats
#define PBV_OFF  69648     // 1200
#define PBI_OFF  70848     // 1200
#define G_OFF    73728     // uint32 region: 2 tables * 16*2048*64 = 4194304 u32 (16 MB)

// ---------- threefry2x32 (JAX partitionable) ----------
__host__ __device__ inline void tf2x32(uint32_t k0, uint32_t k1,
                                       uint32_t x0, uint32_t x1,
                                       uint32_t* o0, uint32_t* o1) {
  const uint32_t rotA[4] = {13u, 15u, 26u, 6u};
  const uint32_t rotB[4] = {17u, 29u, 16u, 24u};
  uint32_t ks0 = k0, ks1 = k1, ks2 = k0 ^ k1 ^ 0x1BD11BDAu;
  x0 += ks0; x1 += ks1;
#pragma unroll
  for (int g = 0; g < 5; ++g) {
    const uint32_t* r = (g & 1) ? rotB : rotA;
#pragma unroll
    for (int i = 0; i < 4; ++i) {
      x0 += x1;
      x1 = (x1 << r[i]) | (x1 >> (32u - r[i]));
      x1 ^= x0;
    }
    uint32_t a0 = (g % 3 == 0) ? ks1 : ((g % 3 == 1) ? ks2 : ks0);
    uint32_t a1 = (g % 3 == 0) ? ks2 : ((g % 3 == 1) ? ks0 : ks1);
    x0 += a0;
    x1 += a1 + (uint32_t)(g + 1);
  }
  *o0 = x0; *o1 = x1;
}

__device__ inline float blo(uint32_t v) { return __uint_as_float(v << 16); }
__device__ inline float bhi(uint32_t v) { return __uint_as_float(v & 0xffff0000u); }
__device__ inline uint16_t f2bu(float f) {
  bf16 h = __float2bfloat16(f);
  uint16_t u; __builtin_memcpy(&u, &h, 2); return u;
}
__device__ inline float gumbel(uint32_t ka, uint32_t kb, uint32_t flat) {
  uint32_t o0, o1;
  tf2x32(ka, kb, 0u, flat, &o0, &o1);
  uint32_t bits = o0 ^ o1;
  float u0 = __uint_as_float((bits >> 9) | 0x3f800000u) - 1.0f;
  float uu = fmaxf(1e-10f, u0 + 1e-10f);
  return -logf(-logf(uu));
}

// ---------- h = hidden @ Wm^T + Wb ; u = h ----------
__global__ void k_h(const float* __restrict__ hidden, const float* __restrict__ Wm,
                    const float* __restrict__ Wb, float* __restrict__ h,
                    float* __restrict__ u) {
  int b = blockIdx.x, j = threadIdx.x;
  const float4* wr = (const float4*)(Wm + (size_t)j * EDIM);
  const float4* hr = (const float4*)(hidden + (size_t)b * EDIM);
  float acc = Wb[j];
#pragma unroll
  for (int i = 0; i < 32; ++i) {
    float4 w4 = wr[i], h4 = hr[i];
    acc += w4.x * h4.x + w4.y * h4.y + w4.z * h4.z + w4.w * h4.w;
  }
  h[b * EDIM + j] = acc;
  u[b * EDIM + j] = acc;
}

// ---------- heads: logits to out; per-chunk gumbel-argmax partials to pbv/pbi ----------
__global__ void k_heads(const float* __restrict__ h,
                        const float* __restrict__ W1w, const float* __restrict__ W1b,
                        const float* __restrict__ W3w, const float* __restrict__ W3b,
                        const float* __restrict__ W4w, const float* __restrict__ W4b,
                        float* __restrict__ out, float* __restrict__ pbv,
                        int* __restrict__ pbi,
                        uint32_t k0a, uint32_t k0b, uint32_t k1a, uint32_t k1b,
                        uint32_t k2a, uint32_t k2b) {
  int bid = blockIdx.x, tid = threadIdx.x;
  __shared__ float hb[EDIM];
  __shared__ float sv[256];
  __shared__ int si[256];
  int head, b2, base, cnt, chunk, N;
  const float *W, *bias; size_t lg_off; uint32_t ka, kb;
  if (bid < 400)      { head = 1; b2 = bid / 25; chunk = bid % 25; base = chunk * 160; cnt = 160;
                        W = W3w; bias = W3b; N = 4000; lg_off = 64;     ka = k1a; kb = k1b; }
  else if (bid < 416) { head = 2; b2 = bid - 400; chunk = 0; base = 0; cnt = 200;
                        W = W4w; bias = W4b; N = 200;  lg_off = 128064; ka = k2a; kb = k2b; }
  else                { head = 0; b2 = bid - 416; chunk = 0; base = 0; cnt = 2;
                        W = W1w; bias = W1b; N = 2;    lg_off = 0;      ka = k0a; kb = k0b; }
  if (tid < 128) hb[tid] = h[b2 * EDIM + tid];
  __syncthreads();
  float best = -INFINITY; int bi = 0x7FFFFFFF;
  if (tid < cnt) {
    int c = base + tid;
    const float4* wr = (const float4*)(W + (size_t)c * EDIM);
    const float4* hb4 = (const float4*)hb;
    float acc = bias[c];
#pragma unroll
    for (int i = 0; i < 32; ++i) {
      float4 w4 = wr[i], h4 = hb4[i];
      acc += w4.x * h4.x + w4.y * h4.y + w4.z * h4.z + w4.w * h4.w;
    }
    out[lg_off + (size_t)b2 * N + c] = acc;
    best = acc + gumbel(ka, kb, (uint32_t)(b2 * N + c));
    bi = c;
  }
  sv[tid] = best; si[tid] = bi;
  __syncthreads();
  for (int s2 = 128; s2 > 0; s2 >>= 1) {
    if (tid < s2) {
      float ov = sv[tid + s2]; int oi = si[tid + s2];
      if (ov > sv[tid] || (ov == sv[tid] && oi < si[tid])) { sv[tid] = ov; si[tid] = oi; }
    }
    __syncthreads();
  }
  if (tid == 0) {
    pbv[(head * 16 + b2) * 25 + chunk] = sv[0];
    pbi[(head * 16 + b2) * 25 + chunk] = si[0];
  }
}

// ---------- one-hots: each thread re-scans its (head,b)'s chunk partials ----------
__global__ void k_onehot(const float* __restrict__ pbv, const int* __restrict__ pbi,
                         float* __restrict__ out) {
  int g = blockIdx.x * 256 + threadIdx.x;
  if (g >= 67232) return;
  int head, b2, c; size_t off; int nch;
  if (g < 64000)      { head = 1; b2 = g / 4000; c = g % 4000; off = 64064 + g;          nch = 25; }
  else if (g < 67200) { int gg = g - 64000; head = 2; b2 = gg / 200; c = gg % 200; off = 131264 + gg; nch = 1; }
  else                { int gg = g - 67200; head = 0; b2 = gg >> 1; c = gg & 1;   off = 32 + gg;     nch = 1; }
  float bv = -INFINITY; int bi = 0x7FFFFFFF;
  for (int ch = 0; ch < nch; ++ch) {
    float v = pbv[(head * 16 + b2) * 25 + ch];
    int i2 = pbi[(head * 16 + b2) * 25 + ch];
    if (v > bv || (v == bv && i2 < bi)) { bv = v; bi = i2; }
  }
  out[off] = (c == bi) ? 1.0f : 0.0f;
}

// ---------- gather: t=0 -> l0 directly (f32 dot with u); t=1,2 -> bf16 G ----------
__global__ void k_gather_l0(const int* __restrict__ story, const float* __restrict__ C,
                            const float* __restrict__ u, uint32_t* __restrict__ G,
                            float* __restrict__ l0) {
  int wid = (blockIdx.x << 2) | (threadIdx.x >> 6);  // 0..98303
  int lane = threadIdx.x & 63;
  int t = wid >> 15;
  int bs = wid & 32767;
  int4 idx = ((const int4*)story)[bs];
  const float2* r0 = (const float2*)(C + ((size_t)t * VOCABN + idx.x) * EDIM);
  const float2* r1 = (const float2*)(C + ((size_t)t * VOCABN + idx.y) * EDIM);
  const float2* r2 = (const float2*)(C + ((size_t)t * VOCABN + idx.z) * EDIM);
  const float2* r3 = (const float2*)(C + ((size_t)t * VOCABN + idx.w) * EDIM);
  float2 a = r0[lane], b = r1[lane], c = r2[lane], d = r3[lane];
  float lo = a.x + b.x + c.x + d.x;
  float hi = a.y + b.y + c.y + d.y;
  if (t == 0) {
    float2 uu = ((const float2*)(u + ((bs >> 11) << 7)))[lane];
    float s = lo * uu.x + hi * uu.y;
#pragma unroll
    for (int off = 32; off > 0; off >>= 1) s += __shfl_xor(s, off, 64);
    if (lane == 0) l0[bs] = s;
  } else {
    G[((size_t)(t - 1) * BN * SN + bs) * 64 + lane] =
        (uint32_t)f2bu(lo) | ((uint32_t)f2bu(hi) << 16);
  }
}

// ---------- per-batch fused hops: softmax/u-update/logits x2 + masked sigmoid ----------
__global__ void __launch_bounds__(1024) k_hops(const uint32_t* __restrict__ G,
                                               const float* __restrict__ u_ws,
                                               const float* __restrict__ l0,
                                               const int* __restrict__ lengths,
                                               float* __restrict__ out) {
  const int b = blockIdx.x, tid = threadIdx.x;
  const int wave = tid >> 6, lane = tid & 63;
  __shared__ float row[SN];        // logits -> exp -> p (unnormalized)
  __shared__ float u_l[EDIM];
  __shared__ float acc[16][EDIM];
  __shared__ float red[16];

  for (int s = tid; s < SN; s += 1024) row[s] = l0[b * SN + s];
  if (tid < EDIM) u_l[tid] = u_ws[b * EDIM + tid];
  __syncthreads();

#pragma unroll
  for (int hop = 0; hop < 2; ++hop) {
    const uint32_t* Gt = G + ((size_t)hop * BN + b) * SN * 64;
    // ---- softmax over row (max, exp, sum) ----
    float m = fmaxf(row[tid], row[tid + 1024]);
#pragma unroll
    for (int off = 32; off > 0; off >>= 1) m = fmaxf(m, __shfl_xor(m, off, 64));
    if (lane == 0) red[wave] = m;
    __syncthreads();
    m = red[0];
#pragma unroll
    for (int w = 1; w < 16; ++w) m = fmaxf(m, red[w]);
    float e0 = expf(row[tid] - m), e1 = expf(row[tid + 1024] - m);
    __syncthreads();             // all reads of row done before overwrite
    row[tid] = e0; row[tid + 1024] = e1;
    float sum = e0 + e1;
#pragma unroll
    for (int off = 32; off > 0; off >>= 1) sum += __shfl_xor(sum, off, 64);
    if (lane == 0) red[wave] = sum;
    __syncthreads();
    float S = 0.f;
#pragma unroll
    for (int w = 0; w < 16; ++w) S += red[w];
    float invS = 1.0f / S;

    // ---- u-update: du[e] = sum_s p[s]*Gt[s][e] ; u += du*invS ----
    float a[8] = {0, 0, 0, 0, 0, 0, 0, 0};
    int sub = lane >> 4, le = lane & 15;
#pragma unroll 4
    for (int it = 0; it < 32; ++it) {
      int cell = wave * 128 + it * 4 + sub;
      uint4 v = *(const uint4*)(Gt + (size_t)cell * 64 + le * 4);
      float pp = row[cell];
      a[0] += blo(v.x) * pp; a[1] += bhi(v.x) * pp;
      a[2] += blo(v.y) * pp; a[3] += bhi(v.y) * pp;
      a[4] += blo(v.z) * pp; a[5] += bhi(v.z) * pp;
      a[6] += blo(v.w) * pp; a[7] += bhi(v.w) * pp;
    }
#pragma unroll
    for (int j = 0; j < 8; ++j) {
      a[j] += __shfl_xor(a[j], 16, 64);
      a[j] += __shfl_xor(a[j], 32, 64);
    }
    if (lane < 16) {
#pragma unroll
      for (int j = 0; j < 8; ++j) acc[wave][lane * 8 + j] = a[j];
    }
    __syncthreads();
    if (tid < EDIM) {
      float du = 0.f;
#pragma unroll
      for (int w = 0; w < 16; ++w) du += acc[w][tid];
      u_l[tid] += du * invS;
    }
    __syncthreads();

    // ---- logits with same Gt and updated u ----
    const float4* u4 = (const float4*)u_l;
#pragma unroll 4
    for (int it = 0; it < 32; ++it) {
      int cell = wave * 128 + it * 4 + sub;
      uint4 v = *(const uint4*)(Gt + (size_t)cell * 64 + le * 4);
      float4 ua = u4[le * 2], ub = u4[le * 2 + 1];
      float s = blo(v.x) * ua.x + bhi(v.x) * ua.y + blo(v.y) * ua.z + bhi(v.y) * ua.w
              + blo(v.z) * ub.x + bhi(v.z) * ub.y + blo(v.w) * ub.z + bhi(v.w) * ub.w;
#pragma unroll
      for (int off = 8; off > 0; off >>= 1) s += __shfl_xor(s, off, 64);
      if (le == 0) row[cell] = s;
    }
    __syncthreads();
  }

  // ---- masked sigmoid ----
  int len = lengths[b];
  for (int s = tid; s < SN; s += 1024) {
    float v = row[s];
    out[134464 + b * SN + s] = (s < len) ? 1.0f / (1.0f + expf(-v)) : 0.0f;
  }
}

extern "C" void kernel_launch(void* const* d_in, const int* in_sizes, int n_in,
                              void* d_out, int out_size, void* d_ws, size_t ws_size,
                              hipStream_t stream) {
  const int *story = nullptr, *lengths = nullptr;
  const float *hidden = nullptr, *C = nullptr, *Wm = nullptr, *Wb = nullptr,
              *W1w = nullptr, *W1b = nullptr, *W3w = nullptr, *W3b = nullptr,
              *W4w = nullptr, *W4b = nullptr;
  for (int i = 0; i < n_in; ++i) {
    switch (in_sizes[i]) {
      case 16 * 2048 * 4:    story   = (const int*)d_in[i]; break;
      case 16:               lengths = (const int*)d_in[i]; break;
      case 16 * 128:         hidden  = (const float*)d_in[i]; break;
      case 4 * 100000 * 128: C       = (const float*)d_in[i]; break;
      case 128 * 128:        Wm      = (const float*)d_in[i]; break;
      case 128:              Wb      = (const float*)d_in[i]; break;
      case 2 * 128:          W1w     = (const float*)d_in[i]; break;
      case 2:                W1b     = (const float*)d_in[i]; break;
      case 4000 * 128:       W3w     = (const float*)d_in[i]; break;
      case 4000:             W3b     = (const float*)d_in[i]; break;
      case 200 * 128:        W4w     = (const float*)d_in[i]; break;
      case 200:              W4b     = (const float*)d_in[i]; break;
      default: break;
    }
  }
  float* out = (float*)d_out;
  float* ws  = (float*)d_ws;
  float* h   = ws + H_OFF;
  float* u   = ws + U_OFF;
  float* l0  = ws + L0_OFF;
  float* pbv = ws + PBV_OFF;
  int*   pbi = (int*)(ws + PBI_OFF);
  uint32_t* G = (uint32_t*)(ws + G_OFF);

  uint32_t k0a, k0b, k1a, k1b, k2a, k2b;
  tf2x32(0u, 42u, 0u, 0u, &k0a, &k0b);
  tf2x32(0u, 42u, 0u, 1u, &k1a, &k1b);
  tf2x32(0u, 42u, 0u, 2u, &k2a, &k2b);

  k_h<<<BN, 128, 0, stream>>>(hidden, Wm, Wb, h, u);
  k_heads<<<432, 256, 0, stream>>>(h, W1w, W1b, W3w, W3b, W4w, W4b,
                                   out, pbv, pbi, k0a, k0b, k1a, k1b, k2a, k2b);
  k_onehot<<<263, 256, 0, stream>>>(pbv, pbi, out);
  k_gather_l0<<<3 * BN * SN / 4, 256, 0, stream>>>(story, C, u, G, l0);
  k_hops<<<BN, 1024, 0, stream>>>(G, u, l0, lengths, out);
}